// Round 8
// baseline (181.109 us; speedup 1.0000x reference)
//
#include <hip/hip_runtime.h>
#include <math.h>

// Net_19335942767008 round 8: kill scattered-gather latency. conv2/conv3 stage
// their sample tiles into LDS via coalesced bf16x8 copies (padded cell strides
// for bank spread, 16B-aligned) and gather A-fragments from LDS instead of
// global. fused_dense widened to 512 threads (8 waves) with nt split across
// wave pairs. Math value-identical to validated round 7.

typedef __attribute__((ext_vector_type(8))) short bf16x8;
typedef __attribute__((ext_vector_type(4))) float f32x4;

__device__ __forceinline__ short f2bf(float f) {
  union { float f; unsigned u; } v; v.f = f;
  unsigned r = v.u + 0x7fffu + ((v.u >> 16) & 1u);
  return (short)(r >> 16);
}
__device__ __forceinline__ float bf2f(unsigned short u) {
  union { unsigned u; float f; } v; v.u = ((unsigned)u) << 16;
  return v.f;
}

// ---------- all weight packs in one kernel ----------
__global__ __launch_bounds__(256) void pack_all(
    const float* __restrict__ w_c1, const float* __restrict__ w_c2,
    const float* __restrict__ w_c3, const float* __restrict__ w_fc,
    const float* __restrict__ w_g1, const float* __restrict__ w_g2,
    short* __restrict__ B1, short* __restrict__ B2, short* __restrict__ B3,
    short* __restrict__ Wfc, short* __restrict__ Wg1, short* __restrict__ Wg2) {
  int idx = blockIdx.x * 256 + threadIdx.x;
  if (idx < 2048) {  // B1: [oc][t][ic4], taps 0..8 + zero pad
    int oc = idx >> 6, k = idx & 63;
    int t = k >> 2, ic = k & 3;
    float v = (t < 9 && ic < 3) ? w_c1[(oc * 3 + ic) * 9 + t] : 0.0f;
    B1[idx] = f2bf(v);
  } else if (idx < 20480) {  // B2: [oc][t][ic], IC=32
    int i2 = idx - 2048;
    int oc = i2 / 288, r = i2 - oc * 288;
    int t = r >> 5, ic = r & 31;
    B2[i2] = f2bf(w_c2[(oc * 32 + ic) * 9 + t]);
  } else if (idx < 94208) {  // B3: [oc][t][ic], IC=64
    int i3 = idx - 20480;
    int oc = i3 / 576, r = i3 - oc * 576;
    int t = r >> 6, ic = r & 63;
    B3[i3] = f2bf(w_c3[(oc * 64 + ic) * 9 + t]);
  } else if (idx < 110592) {
    int i = idx - 94208; Wfc[i] = f2bf(w_fc[i]);
  } else if (idx < 126976) {
    int i = idx - 110592; Wg1[i] = f2bf(w_g1[i]);
  } else if (idx < 143360) {
    int i = idx - 126976; Wg2[i] = f2bf(w_g2[i]);
  }
}

// ---------- conv1 MFMA: x [S,3,8,8] f32 -> c1 [S,4,4,32] bf16 (pooled) ----------
__global__ __launch_bounds__(256) void conv1_mfma(
    const float* __restrict__ x, const short* __restrict__ B1,
    const float* __restrict__ bias, const float* __restrict__ g,
    const float* __restrict__ be, short* __restrict__ c1) {
  __shared__ short sx[8 * 400];
  const int tid = threadIdx.x;
  const int s0 = blockIdx.x * 8;
  for (int i = tid; i < 400; i += 256)
    *(uint4*)(sx + i * 8) = (uint4){0, 0, 0, 0};
  __syncthreads();
  for (int p = tid; p < 512; p += 256) {
    const int si = p >> 6, pix = p & 63;
    const int y = pix >> 3, xx2 = pix & 7;
    const float* xb = x + (s0 + si) * 192 + pix;
    ushort4 o;
    o.x = (unsigned short)f2bf(xb[0]);
    o.y = (unsigned short)f2bf(xb[64]);
    o.z = (unsigned short)f2bf(xb[128]);
    o.w = 0;
    *(ushort4*)(sx + si * 400 + ((y + 1) * 10 + xx2 + 1) * 4) = o;
  }
  __syncthreads();
  const int lane = tid & 63, w = tid >> 6;
  const int col = lane & 15, quad = lane >> 4;
  bf16x8 Bf[2][2];
#pragma unroll
  for (int nt = 0; nt < 2; ++nt)
#pragma unroll
    for (int ks = 0; ks < 2; ++ks)
      Bf[nt][ks] = *(const bf16x8*)(B1 + (nt * 16 + col) * 64 + ks * 32 + quad * 8);
  float Abn[2], Cbn[2];
#pragma unroll
  for (int nt = 0; nt < 2; ++nt) {
    int oc = nt * 16 + col;
    float a = g[oc] * rsqrtf(1.0f + 1e-5f);
    Abn[nt] = a;
    Cbn[nt] = fmaf(bias[oc], a, be[oc]);
  }
  const int t0 = 2 * quad, t1 = t0 + 1;
  const int ky0 = t0 / 3, kx0 = t0 - 3 * (t0 / 3);
  const int ky1 = t1 / 3, kx1 = t1 - 3 * (t1 / 3);
  const int m = lane & 15;
  const int pl = m >> 2, sub = m & 3;
  const int dy = sub >> 1, dx = sub & 1;
  const uint2 z2 = {0u, 0u};
#pragma unroll
  for (int sl = 0; sl < 2; ++sl) {
    const int si = w * 2 + sl;
    const int s = s0 + si;
    const short* xb = sx + si * 400;
#pragma unroll
    for (int tile = 0; tile < 4; ++tile) {
      const int pi = tile * 4 + pl;
      const int py = pi >> 2, px = pi & 3;
      const int cy = 2 * py + dy, cx = 2 * px + dx;
      union { bf16x8 v; uint2 u[2]; } a0, a1;
      a0.u[0] = *(const uint2*)(xb + ((cy + ky0) * 10 + cx + kx0) * 4);
      a0.u[1] = *(const uint2*)(xb + ((cy + ky1) * 10 + cx + kx1) * 4);
      uint2 u8 = *(const uint2*)(xb + ((cy + 2) * 10 + cx + 2) * 4);
      a1.u[0] = (quad == 0) ? u8 : z2;
      a1.u[1] = z2;
      f32x4 acc0 = {0, 0, 0, 0}, acc1 = {0, 0, 0, 0};
      acc0 = __builtin_amdgcn_mfma_f32_16x16x32_bf16(a0.v, Bf[0][0], acc0, 0, 0, 0);
      acc0 = __builtin_amdgcn_mfma_f32_16x16x32_bf16(a1.v, Bf[0][1], acc0, 0, 0, 0);
      acc1 = __builtin_amdgcn_mfma_f32_16x16x32_bf16(a0.v, Bf[1][0], acc1, 0, 0, 0);
      acc1 = __builtin_amdgcn_mfma_f32_16x16x32_bf16(a1.v, Bf[1][1], acc1, 0, 0, 0);
      const int piq = tile * 4 + quad;
#pragma unroll
      for (int nt = 0; nt < 2; ++nt) {
        f32x4 acc = nt ? acc1 : acc0;
        float p0 = fmaf(acc[0], Abn[nt], Cbn[nt]);
        float p1 = fmaf(acc[1], Abn[nt], Cbn[nt]);
        float p2 = fmaf(acc[2], Abn[nt], Cbn[nt]);
        float p3 = fmaf(acc[3], Abn[nt], Cbn[nt]);
        float mx = fmaxf(fmaxf(fmaxf(p0, p1), fmaxf(p2, p3)), 0.0f);
        c1[s * 512 + piq * 32 + nt * 16 + col] = f2bf(mx);
      }
    }
  }
}

// ---------- conv2 MFMA: c1 [S,4,4,32] -> c2 [S,2,2,64] bf16, LDS-staged A ----------
// Block = 32 samples; sample stride 640 shorts, cell stride 40 (16B-aligned,
// bank-spread). A-gathers are ds_reads; B2 frags in VGPRs.
__global__ __launch_bounds__(256, 2) void conv2_mfma(
    const short* __restrict__ c1, const short* __restrict__ B2,
    const float* __restrict__ bias, const float* __restrict__ g,
    const float* __restrict__ be, short* __restrict__ c2) {
  __shared__ short sx[32 * 640];  // 40 KB
  const int tid = threadIdx.x;
  const int s0 = blockIdx.x * 32;
#pragma unroll
  for (int it = 0; it < 8; ++it) {
    int c = it * 256 + tid;            // 2048 chunks of 8 shorts
    int s_l = c >> 6, k = c & 63;      // 64 chunks/sample
    int cell = k >> 2, seg = k & 3;    // cell = 32 shorts = 4 chunks
    *(bf16x8*)(sx + s_l * 640 + cell * 40 + seg * 8) =
        *(const bf16x8*)(c1 + s0 * 512 + c * 8);
  }
  const int lane = tid & 63, w = tid >> 6;
  const int col = lane & 15, quad = lane >> 4;
  bf16x8 Bf[4][9];
#pragma unroll
  for (int nt = 0; nt < 4; ++nt)
#pragma unroll
    for (int t = 0; t < 9; ++t)
      Bf[nt][t] = *(const bf16x8*)(B2 + (nt * 16 + col) * 288 + t * 32 + quad * 8);
  float Abn[4], Cbn[4];
#pragma unroll
  for (int nt = 0; nt < 4; ++nt) {
    int oc = nt * 16 + col;
    float a = g[oc] * rsqrtf(1.0f + 1e-5f);
    Abn[nt] = a;
    Cbn[nt] = fmaf(bias[oc], a, be[oc]);
  }
  const int m = lane & 15;
  const int q2 = m >> 2, sub = m & 3;
  const int cy = 2 * (q2 >> 1) + (sub >> 1);
  const int cx = 2 * (q2 & 1) + (sub & 1);
  int off[9];
  bool valid[9];
#pragma unroll
  for (int t = 0; t < 9; ++t) {
    int ky = t / 3, kx = t - 3 * (t / 3);
    int yy = cy + ky - 1, xx = cx + kx - 1;
    valid[t] = ((unsigned)yy < 4u) && ((unsigned)xx < 4u);
    int yc = min(max(yy, 0), 3), xc = min(max(xx, 0), 3);
    off[t] = (yc * 4 + xc) * 40 + quad * 8;   // padded cell stride
  }
  const bf16x8 zf = {0, 0, 0, 0, 0, 0, 0, 0};
  __syncthreads();
#pragma unroll 1
  for (int si = 0; si < 8; ++si) {
    const int s_l = w * 8 + si;
    const short* ib = sx + s_l * 640;
    f32x4 acc[4];
#pragma unroll
    for (int nt = 0; nt < 4; ++nt) acc[nt] = (f32x4){0, 0, 0, 0};
#pragma unroll
    for (int t = 0; t < 9; ++t) {
      bf16x8 a = *(const bf16x8*)(ib + off[t]);
      if (!valid[t]) a = zf;
#pragma unroll
      for (int nt = 0; nt < 4; ++nt)
        acc[nt] = __builtin_amdgcn_mfma_f32_16x16x32_bf16(a, Bf[nt][t], acc[nt], 0, 0, 0);
    }
    short* ob = c2 + (s0 + s_l) * 256;
#pragma unroll
    for (int nt = 0; nt < 4; ++nt) {
      float p0 = fmaf(acc[nt][0], Abn[nt], Cbn[nt]);
      float p1 = fmaf(acc[nt][1], Abn[nt], Cbn[nt]);
      float p2 = fmaf(acc[nt][2], Abn[nt], Cbn[nt]);
      float p3 = fmaf(acc[nt][3], Abn[nt], Cbn[nt]);
      float mx = fmaxf(fmaxf(fmaxf(p0, p1), fmaxf(p2, p3)), 0.0f);
      ob[quad * 64 + nt * 16 + col] = f2bf(mx);
    }
  }
}

// ---------- conv3 MFMA: c2 [S,2,2,64] -> c3 [S,128] bf16, LDS-staged A ----------
__global__ __launch_bounds__(256) void conv3_mfma(
    const short* __restrict__ c2, const short* __restrict__ B3,
    const float* __restrict__ bias, const float* __restrict__ g,
    const float* __restrict__ be, short* __restrict__ c3) {
  __shared__ short sB[32 * 584];   // 37.4 KB
  __shared__ short sA[16 * 296];   // 9.5 KB; cell stride 72, sample stride 296
  const int tid = threadIdx.x;
  const int s0 = blockIdx.x * 16;
#pragma unroll
  for (int it = 0; it < 2; ++it) {
    int c = it * 256 + tid;          // 512 chunks of 8 shorts
    int s_l = c >> 5, k = c & 31;    // 32 chunks/sample
    int cell = k >> 3, seg = k & 7;  // cell = 64 shorts = 8 chunks
    *(bf16x8*)(sA + s_l * 296 + cell * 72 + seg * 8) =
        *(const bf16x8*)(c2 + s0 * 256 + c * 8);
  }
  __syncthreads();
  const int lane = tid & 63, w = tid >> 6;
  const int col = lane & 15, quad = lane >> 4;
  const int m = lane & 15;
  const int cp = m & 3, sl = m >> 2;
  const int cy = cp >> 1, cx = cp & 1;
  const short* ib = sA + (w * 4 + sl) * 296;
  bf16x8 A[18];
  const bf16x8 zf = {0, 0, 0, 0, 0, 0, 0, 0};
#pragma unroll
  for (int ks = 0; ks < 18; ++ks) {
    int t = ks >> 1;
    int ky = t / 3, kx = t - 3 * (t / 3);
    int iy = cy + ky - 1, ix = cx + kx - 1;
    bool valid = ((unsigned)iy < 2u) && ((unsigned)ix < 2u);
    int iyc = min(max(iy, 0), 1), ixc = min(max(ix, 0), 1);
    bf16x8 a = *(const bf16x8*)(ib + (iyc * 2 + ixc) * 72 + (ks & 1) * 32 + quad * 8);
    A[ks] = valid ? a : zf;
  }
  f32x4 acc[8];
#pragma unroll
  for (int i = 0; i < 8; ++i) acc[i] = (f32x4){0, 0, 0, 0};
#pragma unroll
  for (int ng = 0; ng < 4; ++ng) {
    __syncthreads();
#pragma unroll
    for (int it = 0; it < 9; ++it) {
      int cidx = it * 256 + tid;
      int row = cidx / 72, seg = cidx - row * 72;
      *(bf16x8*)(sB + row * 584 + seg * 8) =
          *(const bf16x8*)(B3 + (ng * 32 + row) * 576 + seg * 8);
    }
    __syncthreads();
#pragma unroll
    for (int nt = 0; nt < 2; ++nt) {
      const int nB = (nt * 16 + col) * 584 + quad * 8;
#pragma unroll
      for (int ks = 0; ks < 18; ++ks) {
        bf16x8 b = *(const bf16x8*)(sB + nB + ks * 32);
        acc[ng * 2 + nt] =
            __builtin_amdgcn_mfma_f32_16x16x32_bf16(A[ks], b, acc[ng * 2 + nt], 0, 0, 0);
      }
    }
  }
  const int sample = s0 + w * 4 + quad;
#pragma unroll
  for (int i = 0; i < 8; ++i) {
    int oc = (i >> 1) * 32 + (i & 1) * 16 + col;
    float a = g[oc] * rsqrtf(1.0f + 1e-5f);
    float cc = fmaf(bias[oc], a, be[oc]);
    float p0 = fmaf(acc[i][0], a, cc);
    float p1 = fmaf(acc[i][1], a, cc);
    float p2 = fmaf(acc[i][2], a, cc);
    float p3 = fmaf(acc[i][3], a, cc);
    float mx = fmaxf(fmaxf(fmaxf(p0, p1), fmaxf(p2, p3)), 0.0f);
    c3[sample * 128 + oc] = f2bf(mx);
  }
}

// ---------- fused dense tail: one block (512 thr, 8 waves) per batch ----------
// nt dimension split across wave pairs: wave w8 -> row-group rg=w8>>1, half nh=w8&1.
__global__ __launch_bounds__(512) void fused_dense(
    const short* __restrict__ c3, const float* __restrict__ gso,
    const short* __restrict__ Wfc, const short* __restrict__ Wg1,
    const short* __restrict__ Wg2, const float* __restrict__ b_fc,
    const float* __restrict__ b_g1, const float* __restrict__ b_g2,
    const float* __restrict__ w_o, const float* __restrict__ b_o,
    float* __restrict__ out) {
  __shared__ short sAct[64 * 136];
  __shared__ short sT[128 * 72];
  __shared__ short sAhat[64 * 72];
  __shared__ float sDinv[64];
  __shared__ float sWo[640];
  const int tid = threadIdx.x;
  const int b = blockIdx.x;
  float* sG = (float*)sT;
  for (int i = tid; i < 4096; i += 512) sG[i] = gso[b * 4096 + i];
  for (int i = tid; i < 640; i += 512) sWo[i] = w_o[i];
  __syncthreads();
  if (tid < 64) {
    float ssum = 1.0f;
    for (int j = 0; j < 64; ++j) ssum += sG[j * 64 + tid];
    sDinv[tid] = rsqrtf(ssum);
  }
  __syncthreads();
  for (int i = tid; i < 4096; i += 512) {
    int r = i >> 6, c = i & 63;
    float v = sDinv[r] * (sG[i] + (r == c ? 1.0f : 0.0f)) * sDinv[c];
    sAhat[r * 72 + c] = f2bf(v);
  }
  for (int i = tid; i < 1024; i += 512) {
    int r = i >> 4, seg = i & 15;
    *(bf16x8*)(sAct + r * 136 + seg * 8) =
        *(const bf16x8*)(c3 + (b * 64 + r) * 128 + seg * 8);
  }
  __syncthreads();
  const int lane = tid & 63, w8 = tid >> 6;  // 8 waves
  const int rg = w8 >> 1, nh = w8 & 1;       // row-group 0..3, n-half 0..1
  const int col = lane & 15, quad = lane >> 4;
  const int arow = (rg * 16 + col) * 136;
  const int crow0 = (rg * 16 + quad * 4) * 136;
  bf16x8 A[4];
  f32x4 acc[4];

  // ---- FC ----
#pragma unroll
  for (int ks = 0; ks < 4; ++ks)
    A[ks] = *(const bf16x8*)(sAct + arow + ks * 32 + quad * 8);
  __syncthreads();
#pragma unroll
  for (int i = 0; i < 4; ++i) acc[i] = (f32x4){0, 0, 0, 0};
#pragma unroll
  for (int ntl = 0; ntl < 4; ++ntl) {
    const int n = (nh * 4 + ntl) * 16 + col;
#pragma unroll
    for (int ks = 0; ks < 4; ++ks) {
      bf16x8 bb = *(const bf16x8*)(Wfc + n * 128 + ks * 32 + quad * 8);
      acc[ntl] = __builtin_amdgcn_mfma_f32_16x16x32_bf16(A[ks], bb, acc[ntl], 0, 0, 0);
    }
  }
#pragma unroll
  for (int ntl = 0; ntl < 4; ++ntl) {
    const int n = (nh * 4 + ntl) * 16 + col;
    const float bv = b_fc[n];
#pragma unroll
    for (int reg = 0; reg < 4; ++reg)
      sAct[crow0 + reg * 136 + n] = f2bf(fmaxf(acc[ntl][reg] + bv, 0.0f));
  }
  __syncthreads();

  // ---- G1 -> sT (transposed) ----
#pragma unroll
  for (int ks = 0; ks < 4; ++ks)
    A[ks] = *(const bf16x8*)(sAct + arow + ks * 32 + quad * 8);
#pragma unroll
  for (int i = 0; i < 4; ++i) acc[i] = (f32x4){0, 0, 0, 0};
#pragma unroll
  for (int ntl = 0; ntl < 4; ++ntl) {
    const int n = (nh * 4 + ntl) * 16 + col;
#pragma unroll
    for (int ks = 0; ks < 4; ++ks) {
      bf16x8 bb = *(const bf16x8*)(Wg1 + n * 128 + ks * 32 + quad * 8);
      acc[ntl] = __builtin_amdgcn_mfma_f32_16x16x32_bf16(A[ks], bb, acc[ntl], 0, 0, 0);
    }
  }
#pragma unroll
  for (int ntl = 0; ntl < 4; ++ntl) {
    const int n = (nh * 4 + ntl) * 16 + col;
    ushort4 pk;
    pk.x = (unsigned short)f2bf(acc[ntl][0]);
    pk.y = (unsigned short)f2bf(acc[ntl][1]);
    pk.z = (unsigned short)f2bf(acc[ntl][2]);
    pk.w = (unsigned short)f2bf(acc[ntl][3]);
    *(ushort4*)(sT + n * 72 + rg * 16 + quad * 4) = pk;
  }
  __syncthreads();

  // ---- AGG1 ----
  bf16x8 Ah[2];
#pragma unroll
  for (int ks = 0; ks < 2; ++ks)
    Ah[ks] = *(const bf16x8*)(sAhat + (rg * 16 + col) * 72 + ks * 32 + quad * 8);
#pragma unroll
  for (int i = 0; i < 4; ++i) acc[i] = (f32x4){0, 0, 0, 0};
#pragma unroll
  for (int ntl = 0; ntl < 4; ++ntl) {
    const int n = (nh * 4 + ntl) * 16 + col;
#pragma unroll
    for (int ks = 0; ks < 2; ++ks) {
      bf16x8 bb = *(const bf16x8*)(sT + n * 72 + ks * 32 + quad * 8);
      acc[ntl] = __builtin_amdgcn_mfma_f32_16x16x32_bf16(Ah[ks], bb, acc[ntl], 0, 0, 0);
    }
  }
#pragma unroll
  for (int ntl = 0; ntl < 4; ++ntl) {
    const int n = (nh * 4 + ntl) * 16 + col;
    const float bv = b_g1[n];
#pragma unroll
    for (int reg = 0; reg < 4; ++reg)
      sAct[crow0 + reg * 136 + n] = f2bf(fmaxf(acc[ntl][reg] + bv, 0.0f));
  }
  __syncthreads();

  // ---- G2 -> sT ----
#pragma unroll
  for (int ks = 0; ks < 4; ++ks)
    A[ks] = *(const bf16x8*)(sAct + arow + ks * 32 + quad * 8);
#pragma unroll
  for (int i = 0; i < 4; ++i) acc[i] = (f32x4){0, 0, 0, 0};
#pragma unroll
  for (int ntl = 0; ntl < 4; ++ntl) {
    const int n = (nh * 4 + ntl) * 16 + col;
#pragma unroll
    for (int ks = 0; ks < 4; ++ks) {
      bf16x8 bb = *(const bf16x8*)(Wg2 + n * 128 + ks * 32 + quad * 8);
      acc[ntl] = __builtin_amdgcn_mfma_f32_16x16x32_bf16(A[ks], bb, acc[ntl], 0, 0, 0);
    }
  }
#pragma unroll
  for (int ntl = 0; ntl < 4; ++ntl) {
    const int n = (nh * 4 + ntl) * 16 + col;
    ushort4 pk;
    pk.x = (unsigned short)f2bf(acc[ntl][0]);
    pk.y = (unsigned short)f2bf(acc[ntl][1]);
    pk.z = (unsigned short)f2bf(acc[ntl][2]);
    pk.w = (unsigned short)f2bf(acc[ntl][3]);
    *(ushort4*)(sT + n * 72 + rg * 16 + quad * 4) = pk;
  }
  __syncthreads();

  // ---- AGG2 ----
#pragma unroll
  for (int i = 0; i < 4; ++i) acc[i] = (f32x4){0, 0, 0, 0};
#pragma unroll
  for (int ntl = 0; ntl < 4; ++ntl) {
    const int n = (nh * 4 + ntl) * 16 + col;
#pragma unroll
    for (int ks = 0; ks < 2; ++ks) {
      bf16x8 bb = *(const bf16x8*)(sT + n * 72 + ks * 32 + quad * 8);
      acc[ntl] = __builtin_amdgcn_mfma_f32_16x16x32_bf16(Ah[ks], bb, acc[ntl], 0, 0, 0);
    }
  }
#pragma unroll
  for (int ntl = 0; ntl < 4; ++ntl) {
    const int n = (nh * 4 + ntl) * 16 + col;
    const float bv = b_g2[n];
#pragma unroll
    for (int reg = 0; reg < 4; ++reg)
      sAct[crow0 + reg * 136 + n] = f2bf(fmaxf(acc[ntl][reg] + bv, 0.0f));
  }
  __syncthreads();

  // ---- HEAD: 320 threads, one (agent, out) each ----
  if (tid < 320) {
    const int j = tid / 5, o = tid - 5 * j;
    float a0 = 0.0f;
#pragma unroll
    for (int k8 = 0; k8 < 16; ++k8) {
      union { bf16x8 v; unsigned short u[8]; } h;
      h.v = *(const bf16x8*)(sAct + j * 136 + k8 * 8);
#pragma unroll
      for (int jj = 0; jj < 8; ++jj)
        a0 = fmaf(bf2f(h.u[jj]), sWo[o * 128 + k8 * 8 + jj], a0);
    }
    out[(b * 64 + j) * 5 + o] = a0 + b_o[o];
  }
}

extern "C" void kernel_launch(void* const* d_in, const int* in_sizes, int n_in,
                              void* d_out, int out_size, void* d_ws, size_t ws_size,
                              hipStream_t stream) {
  const float* x    = (const float*)d_in[0];
  const float* gso  = (const float*)d_in[1];
  const float* w_c1 = (const float*)d_in[2];
  const float* b_c1 = (const float*)d_in[3];
  const float* g_b1 = (const float*)d_in[4];
  const float* e_b1 = (const float*)d_in[5];
  const float* w_c2 = (const float*)d_in[6];
  const float* b_c2 = (const float*)d_in[7];
  const float* g_b2 = (const float*)d_in[8];
  const float* e_b2 = (const float*)d_in[9];
  const float* w_c3 = (const float*)d_in[10];
  const float* b_c3 = (const float*)d_in[11];
  const float* g_b3 = (const float*)d_in[12];
  const float* e_b3 = (const float*)d_in[13];
  const float* w_fc = (const float*)d_in[14];
  const float* b_fc = (const float*)d_in[15];
  const float* w_g1 = (const float*)d_in[16];
  const float* b_g1 = (const float*)d_in[17];
  const float* w_g2 = (const float*)d_in[18];
  const float* b_g2 = (const float*)d_in[19];
  const float* w_o  = (const float*)d_in[20];
  const float* b_o  = (const float*)d_in[21];
  float* out = (float*)d_out;
  char* ws = (char*)d_ws;

  // workspace layout (bytes) — NO ALIASING, total 29.65 MB
  short* c1  = (short*)(ws + 0);          // 16,777,216
  short* c2  = (short*)(ws + 16777216);   //  8,388,608
  short* c3  = (short*)(ws + 25165824);   //  4,194,304
  short* B1  = (short*)(ws + 29360128);   //  4,096
  short* B2  = (short*)(ws + 29364224);   //  36,864
  short* B3  = (short*)(ws + 29401088);   //  147,456
  short* Wfc = (short*)(ws + 29548544);   //  32,768
  short* Wg1 = (short*)(ws + 29581312);   //  32,768
  short* Wg2 = (short*)(ws + 29614080);   //  32,768

  pack_all<<<560, 256, 0, stream>>>(w_c1, w_c2, w_c3, w_fc, w_g1, w_g2,
                                    B1, B2, B3, Wfc, Wg1, Wg2);
  conv1_mfma<<<2048, 256, 0, stream>>>(x, B1, b_c1, g_b1, e_b1, c1);
  conv2_mfma<<<512, 256, 0, stream>>>(c1, B2, b_c2, g_b2, e_b2, c2);
  conv3_mfma<<<1024, 256, 0, stream>>>(c2, B3, b_c3, g_b3, e_b3, c3);
  fused_dense<<<256, 512, 0, stream>>>(c3, gso, Wfc, Wg1, Wg2, b_fc, b_g1,
                                       b_g2, w_o, b_o, out);
}

// Round 9
// 177.092 us; speedup vs baseline: 1.0227x; 1.0227x over previous
//
#include <hip/hip_runtime.h>
#include <math.h>

// Net_19335942767008 round 9: conv1+conv2+conv3 fused into ONE kernel
// (16 samples/block); c1,c2 intermediates never leave LDS. Input frame and
// B3-chunk buffer share one LDS region (union by phase). 3 launches total.
// All arithmetic value-identical to validated rounds 7/8.

typedef __attribute__((ext_vector_type(8))) short bf16x8;
typedef __attribute__((ext_vector_type(4))) float f32x4;

__device__ __forceinline__ short f2bf(float f) {
  union { float f; unsigned u; } v; v.f = f;
  unsigned r = v.u + 0x7fffu + ((v.u >> 16) & 1u);
  return (short)(r >> 16);
}
__device__ __forceinline__ float bf2f(unsigned short u) {
  union { unsigned u; float f; } v; v.u = ((unsigned)u) << 16;
  return v.f;
}

// ---------- all weight packs in one kernel ----------
__global__ __launch_bounds__(256) void pack_all(
    const float* __restrict__ w_c1, const float* __restrict__ w_c2,
    const float* __restrict__ w_c3, const float* __restrict__ w_fc,
    const float* __restrict__ w_g1, const float* __restrict__ w_g2,
    short* __restrict__ B1, short* __restrict__ B2, short* __restrict__ B3,
    short* __restrict__ Wfc, short* __restrict__ Wg1, short* __restrict__ Wg2) {
  int idx = blockIdx.x * 256 + threadIdx.x;
  if (idx < 2048) {  // B1: [oc][t][ic4], taps 0..8 + zero pad
    int oc = idx >> 6, k = idx & 63;
    int t = k >> 2, ic = k & 3;
    float v = (t < 9 && ic < 3) ? w_c1[(oc * 3 + ic) * 9 + t] : 0.0f;
    B1[idx] = f2bf(v);
  } else if (idx < 20480) {  // B2: [oc][t][ic], IC=32
    int i2 = idx - 2048;
    int oc = i2 / 288, r = i2 - oc * 288;
    int t = r >> 5, ic = r & 31;
    B2[i2] = f2bf(w_c2[(oc * 32 + ic) * 9 + t]);
  } else if (idx < 94208) {  // B3: [oc][t][ic], IC=64
    int i3 = idx - 20480;
    int oc = i3 / 576, r = i3 - oc * 576;
    int t = r >> 6, ic = r & 63;
    B3[i3] = f2bf(w_c3[(oc * 64 + ic) * 9 + t]);
  } else if (idx < 110592) {
    int i = idx - 94208; Wfc[i] = f2bf(w_fc[i]);
  } else if (idx < 126976) {
    int i = idx - 110592; Wg1[i] = f2bf(w_g1[i]);
  } else if (idx < 143360) {
    int i = idx - 126976; Wg2[i] = f2bf(w_g2[i]);
  }
}

// ---------- fused conv stack: x [S,3,8,8] -> c3 [S,128] bf16 ----------
// Block = 16 samples. Phase P0: stage padded input frames. P1: conv1 -> sc1
// (LDS). P2: conv2 -> sc2 (LDS). P3: conv3 (B3 streamed in 8x16-row chunks
// through sMix, which aliased the input frames in P0/P1) -> c3 global.
__global__ __launch_bounds__(256, 2) void conv_all(
    const float* __restrict__ x, const short* __restrict__ B1g,
    const short* __restrict__ B2g, const short* __restrict__ B3g,
    const float* __restrict__ b1, const float* __restrict__ g1,
    const float* __restrict__ e1, const float* __restrict__ b2,
    const float* __restrict__ g2, const float* __restrict__ e2,
    const float* __restrict__ b3, const float* __restrict__ g3,
    const float* __restrict__ e3, short* __restrict__ c3) {
  __shared__ short sMix[16 * 584];  // P0/P1: input frames (16*400); P3: B3 chunk (16*584)
  __shared__ short sc1[16 * 640];   // conv1 out, cell stride 40
  __shared__ short sc2[16 * 296];   // conv2 out, cell stride 72
  const int tid = threadIdx.x;
  const int s0 = blockIdx.x * 16;
  const int lane = tid & 63, w = tid >> 6;
  const int col = lane & 15, quad = lane >> 4;
  const int m = lane & 15;

  // ---- P0: zero + fill 16 padded [10][10][4] bf16 frames ----
  for (int i = tid; i < 800; i += 256)
    *(uint4*)(sMix + i * 8) = (uint4){0, 0, 0, 0};
  __syncthreads();
#pragma unroll
  for (int it = 0; it < 4; ++it) {
    int p = it * 256 + tid;  // 1024 pixel tasks
    int si = p >> 6, pix = p & 63;
    int y = pix >> 3, xx2 = pix & 7;
    const float* xb = x + (s0 + si) * 192 + pix;
    ushort4 o;
    o.x = (unsigned short)f2bf(xb[0]);
    o.y = (unsigned short)f2bf(xb[64]);
    o.z = (unsigned short)f2bf(xb[128]);
    o.w = 0;
    *(ushort4*)(sMix + si * 400 + ((y + 1) * 10 + xx2 + 1) * 4) = o;
  }
  __syncthreads();

  // ---- P1: conv1 (wave w -> samples w*4..w*4+3) ----
  {
    bf16x8 Bf[2][2];
#pragma unroll
    for (int nt = 0; nt < 2; ++nt)
#pragma unroll
      for (int ks = 0; ks < 2; ++ks)
        Bf[nt][ks] = *(const bf16x8*)(B1g + (nt * 16 + col) * 64 + ks * 32 + quad * 8);
    float Abn[2], Cbn[2];
#pragma unroll
    for (int nt = 0; nt < 2; ++nt) {
      int oc = nt * 16 + col;
      float a = g1[oc] * rsqrtf(1.0f + 1e-5f);
      Abn[nt] = a;
      Cbn[nt] = fmaf(b1[oc], a, e1[oc]);
    }
    const int t0 = 2 * quad, t1 = t0 + 1;
    const int ky0 = t0 / 3, kx0 = t0 - 3 * (t0 / 3);
    const int ky1 = t1 / 3, kx1 = t1 - 3 * (t1 / 3);
    const int pl = m >> 2, sub = m & 3;
    const int dy = sub >> 1, dx = sub & 1;
    const uint2 z2 = {0u, 0u};
#pragma unroll
    for (int sl = 0; sl < 4; ++sl) {
      const int si = w * 4 + sl;
      const short* xb = sMix + si * 400;
#pragma unroll
      for (int tile = 0; tile < 4; ++tile) {
        const int pi = tile * 4 + pl;
        const int py = pi >> 2, px = pi & 3;
        const int cy = 2 * py + dy, cx = 2 * px + dx;
        union { bf16x8 v; uint2 u[2]; } a0, a1;
        a0.u[0] = *(const uint2*)(xb + ((cy + ky0) * 10 + cx + kx0) * 4);
        a0.u[1] = *(const uint2*)(xb + ((cy + ky1) * 10 + cx + kx1) * 4);
        uint2 u8 = *(const uint2*)(xb + ((cy + 2) * 10 + cx + 2) * 4);
        a1.u[0] = (quad == 0) ? u8 : z2;
        a1.u[1] = z2;
        f32x4 acc0 = {0, 0, 0, 0}, acc1 = {0, 0, 0, 0};
        acc0 = __builtin_amdgcn_mfma_f32_16x16x32_bf16(a0.v, Bf[0][0], acc0, 0, 0, 0);
        acc0 = __builtin_amdgcn_mfma_f32_16x16x32_bf16(a1.v, Bf[0][1], acc0, 0, 0, 0);
        acc1 = __builtin_amdgcn_mfma_f32_16x16x32_bf16(a0.v, Bf[1][0], acc1, 0, 0, 0);
        acc1 = __builtin_amdgcn_mfma_f32_16x16x32_bf16(a1.v, Bf[1][1], acc1, 0, 0, 0);
        const int piq = tile * 4 + quad;
#pragma unroll
        for (int nt = 0; nt < 2; ++nt) {
          f32x4 acc = nt ? acc1 : acc0;
          float p0 = fmaf(acc[0], Abn[nt], Cbn[nt]);
          float p1 = fmaf(acc[1], Abn[nt], Cbn[nt]);
          float p2 = fmaf(acc[2], Abn[nt], Cbn[nt]);
          float p3 = fmaf(acc[3], Abn[nt], Cbn[nt]);
          float mx = fmaxf(fmaxf(fmaxf(p0, p1), fmaxf(p2, p3)), 0.0f);
          sc1[si * 640 + piq * 40 + nt * 16 + col] = f2bf(mx);
        }
      }
    }
  }
  __syncthreads();

  // ---- P2: conv2 (wave w -> samples w*4..w*4+3), A from sc1 ----
  {
    bf16x8 Bf[4][9];
#pragma unroll
    for (int nt = 0; nt < 4; ++nt)
#pragma unroll
      for (int t = 0; t < 9; ++t)
        Bf[nt][t] = *(const bf16x8*)(B2g + (nt * 16 + col) * 288 + t * 32 + quad * 8);
    float Abn[4], Cbn[4];
#pragma unroll
    for (int nt = 0; nt < 4; ++nt) {
      int oc = nt * 16 + col;
      float a = g2[oc] * rsqrtf(1.0f + 1e-5f);
      Abn[nt] = a;
      Cbn[nt] = fmaf(b2[oc], a, e2[oc]);
    }
    const int q2 = m >> 2, sub = m & 3;
    const int cy = 2 * (q2 >> 1) + (sub >> 1);
    const int cx = 2 * (q2 & 1) + (sub & 1);
    int off[9];
    bool valid[9];
#pragma unroll
    for (int t = 0; t < 9; ++t) {
      int ky = t / 3, kx = t - 3 * (t / 3);
      int yy = cy + ky - 1, xx = cx + kx - 1;
      valid[t] = ((unsigned)yy < 4u) && ((unsigned)xx < 4u);
      int yc = min(max(yy, 0), 3), xc = min(max(xx, 0), 3);
      off[t] = (yc * 4 + xc) * 40 + quad * 8;
    }
    const bf16x8 zf = {0, 0, 0, 0, 0, 0, 0, 0};
#pragma unroll
    for (int sl = 0; sl < 4; ++sl) {
      const int si = w * 4 + sl;
      const short* ib = sc1 + si * 640;
      f32x4 acc[4];
#pragma unroll
      for (int nt = 0; nt < 4; ++nt) acc[nt] = (f32x4){0, 0, 0, 0};
#pragma unroll
      for (int t = 0; t < 9; ++t) {
        bf16x8 a = *(const bf16x8*)(ib + off[t]);
        if (!valid[t]) a = zf;
#pragma unroll
        for (int nt = 0; nt < 4; ++nt)
          acc[nt] = __builtin_amdgcn_mfma_f32_16x16x32_bf16(a, Bf[nt][t], acc[nt], 0, 0, 0);
      }
#pragma unroll
      for (int nt = 0; nt < 4; ++nt) {
        float p0 = fmaf(acc[nt][0], Abn[nt], Cbn[nt]);
        float p1 = fmaf(acc[nt][1], Abn[nt], Cbn[nt]);
        float p2 = fmaf(acc[nt][2], Abn[nt], Cbn[nt]);
        float p3 = fmaf(acc[nt][3], Abn[nt], Cbn[nt]);
        float mx = fmaxf(fmaxf(fmaxf(p0, p1), fmaxf(p2, p3)), 0.0f);
        sc2[si * 296 + quad * 72 + nt * 16 + col] = f2bf(mx);
      }
    }
  }
  __syncthreads();

  // ---- P3: conv3, A from sc2, B3 streamed in 8 chunks of 16 oc ----
  {
    const int cp = m & 3, sl3 = m >> 2;
    const int cy = cp >> 1, cx = cp & 1;
    const short* ib = sc2 + (w * 4 + sl3) * 296;
    bf16x8 A[18];
    const bf16x8 zf = {0, 0, 0, 0, 0, 0, 0, 0};
#pragma unroll
    for (int ks = 0; ks < 18; ++ks) {
      int t = ks >> 1;
      int ky = t / 3, kx = t - 3 * (t / 3);
      int iy = cy + ky - 1, ix = cx + kx - 1;
      bool valid = ((unsigned)iy < 2u) && ((unsigned)ix < 2u);
      int iyc = min(max(iy, 0), 1), ixc = min(max(ix, 0), 1);
      bf16x8 a = *(const bf16x8*)(ib + (iyc * 2 + ixc) * 72 + (ks & 1) * 32 + quad * 8);
      A[ks] = valid ? a : zf;
    }
    f32x4 acc[8];
#pragma unroll
    for (int i = 0; i < 8; ++i) acc[i] = (f32x4){0, 0, 0, 0};
#pragma unroll 1
    for (int ng = 0; ng < 8; ++ng) {
      __syncthreads();
      for (int c = tid; c < 1152; c += 256) {  // 16 rows x 72 chunks of 8
        int row = c / 72, seg = c - row * 72;
        *(bf16x8*)(sMix + row * 584 + seg * 8) =
            *(const bf16x8*)(B3g + (ng * 16 + row) * 576 + seg * 8);
      }
      __syncthreads();
      const int nB = col * 584 + quad * 8;
#pragma unroll
      for (int ks = 0; ks < 18; ++ks) {
        bf16x8 b = *(const bf16x8*)(sMix + nB + ks * 32);
        acc[ng] = __builtin_amdgcn_mfma_f32_16x16x32_bf16(A[ks], b, acc[ng], 0, 0, 0);
      }
    }
    const int sample = s0 + w * 4 + quad;
#pragma unroll
    for (int ng = 0; ng < 8; ++ng) {
      int oc = ng * 16 + col;
      float a = g3[oc] * rsqrtf(1.0f + 1e-5f);
      float cc = fmaf(b3[oc], a, e3[oc]);
      float p0 = fmaf(acc[ng][0], a, cc);
      float p1 = fmaf(acc[ng][1], a, cc);
      float p2 = fmaf(acc[ng][2], a, cc);
      float p3 = fmaf(acc[ng][3], a, cc);
      float mx = fmaxf(fmaxf(fmaxf(p0, p1), fmaxf(p2, p3)), 0.0f);
      c3[sample * 128 + oc] = f2bf(mx);
    }
  }
}

// ---------- fused dense tail: one block (512 thr, 8 waves) per batch ----------
__global__ __launch_bounds__(512) void fused_dense(
    const short* __restrict__ c3, const float* __restrict__ gso,
    const short* __restrict__ Wfc, const short* __restrict__ Wg1,
    const short* __restrict__ Wg2, const float* __restrict__ b_fc,
    const float* __restrict__ b_g1, const float* __restrict__ b_g2,
    const float* __restrict__ w_o, const float* __restrict__ b_o,
    float* __restrict__ out) {
  __shared__ short sAct[64 * 136];
  __shared__ short sT[128 * 72];
  __shared__ short sAhat[64 * 72];
  __shared__ float sDinv[64];
  __shared__ float sWo[640];
  const int tid = threadIdx.x;
  const int b = blockIdx.x;
  float* sG = (float*)sT;
  for (int i = tid; i < 4096; i += 512) sG[i] = gso[b * 4096 + i];
  for (int i = tid; i < 640; i += 512) sWo[i] = w_o[i];
  __syncthreads();
  if (tid < 64) {
    float ssum = 1.0f;
    for (int j = 0; j < 64; ++j) ssum += sG[j * 64 + tid];
    sDinv[tid] = rsqrtf(ssum);
  }
  __syncthreads();
  for (int i = tid; i < 4096; i += 512) {
    int r = i >> 6, c = i & 63;
    float v = sDinv[r] * (sG[i] + (r == c ? 1.0f : 0.0f)) * sDinv[c];
    sAhat[r * 72 + c] = f2bf(v);
  }
  for (int i = tid; i < 1024; i += 512) {
    int r = i >> 4, seg = i & 15;
    *(bf16x8*)(sAct + r * 136 + seg * 8) =
        *(const bf16x8*)(c3 + (b * 64 + r) * 128 + seg * 8);
  }
  __syncthreads();
  const int lane = tid & 63, w8 = tid >> 6;
  const int rg = w8 >> 1, nh = w8 & 1;
  const int col = lane & 15, quad = lane >> 4;
  const int arow = (rg * 16 + col) * 136;
  const int crow0 = (rg * 16 + quad * 4) * 136;
  bf16x8 A[4];
  f32x4 acc[4];

  // ---- FC ----
#pragma unroll
  for (int ks = 0; ks < 4; ++ks)
    A[ks] = *(const bf16x8*)(sAct + arow + ks * 32 + quad * 8);
  __syncthreads();
#pragma unroll
  for (int i = 0; i < 4; ++i) acc[i] = (f32x4){0, 0, 0, 0};
#pragma unroll
  for (int ntl = 0; ntl < 4; ++ntl) {
    const int n = (nh * 4 + ntl) * 16 + col;
#pragma unroll
    for (int ks = 0; ks < 4; ++ks) {
      bf16x8 bb = *(const bf16x8*)(Wfc + n * 128 + ks * 32 + quad * 8);
      acc[ntl] = __builtin_amdgcn_mfma_f32_16x16x32_bf16(A[ks], bb, acc[ntl], 0, 0, 0);
    }
  }
#pragma unroll
  for (int ntl = 0; ntl < 4; ++ntl) {
    const int n = (nh * 4 + ntl) * 16 + col;
    const float bv = b_fc[n];
#pragma unroll
    for (int reg = 0; reg < 4; ++reg)
      sAct[crow0 + reg * 136 + n] = f2bf(fmaxf(acc[ntl][reg] + bv, 0.0f));
  }
  __syncthreads();

  // ---- G1 -> sT (transposed) ----
#pragma unroll
  for (int ks = 0; ks < 4; ++ks)
    A[ks] = *(const bf16x8*)(sAct + arow + ks * 32 + quad * 8);
#pragma unroll
  for (int i = 0; i < 4; ++i) acc[i] = (f32x4){0, 0, 0, 0};
#pragma unroll
  for (int ntl = 0; ntl < 4; ++ntl) {
    const int n = (nh * 4 + ntl) * 16 + col;
#pragma unroll
    for (int ks = 0; ks < 4; ++ks) {
      bf16x8 bb = *(const bf16x8*)(Wg1 + n * 128 + ks * 32 + quad * 8);
      acc[ntl] = __builtin_amdgcn_mfma_f32_16x16x32_bf16(A[ks], bb, acc[ntl], 0, 0, 0);
    }
  }
#pragma unroll
  for (int ntl = 0; ntl < 4; ++ntl) {
    const int n = (nh * 4 + ntl) * 16 + col;
    ushort4 pk;
    pk.x = (unsigned short)f2bf(acc[ntl][0]);
    pk.y = (unsigned short)f2bf(acc[ntl][1]);
    pk.z = (unsigned short)f2bf(acc[ntl][2]);
    pk.w = (unsigned short)f2bf(acc[ntl][3]);
    *(ushort4*)(sT + n * 72 + rg * 16 + quad * 4) = pk;
  }
  __syncthreads();

  // ---- AGG1 ----
  bf16x8 Ah[2];
#pragma unroll
  for (int ks = 0; ks < 2; ++ks)
    Ah[ks] = *(const bf16x8*)(sAhat + (rg * 16 + col) * 72 + ks * 32 + quad * 8);
#pragma unroll
  for (int i = 0; i < 4; ++i) acc[i] = (f32x4){0, 0, 0, 0};
#pragma unroll
  for (int ntl = 0; ntl < 4; ++ntl) {
    const int n = (nh * 4 + ntl) * 16 + col;
#pragma unroll
    for (int ks = 0; ks < 2; ++ks) {
      bf16x8 bb = *(const bf16x8*)(sT + n * 72 + ks * 32 + quad * 8);
      acc[ntl] = __builtin_amdgcn_mfma_f32_16x16x32_bf16(Ah[ks], bb, acc[ntl], 0, 0, 0);
    }
  }
#pragma unroll
  for (int ntl = 0; ntl < 4; ++ntl) {
    const int n = (nh * 4 + ntl) * 16 + col;
    const float bv = b_g1[n];
#pragma unroll
    for (int reg = 0; reg < 4; ++reg)
      sAct[crow0 + reg * 136 + n] = f2bf(fmaxf(acc[ntl][reg] + bv, 0.0f));
  }
  __syncthreads();

  // ---- G2 -> sT ----
#pragma unroll
  for (int ks = 0; ks < 4; ++ks)
    A[ks] = *(const bf16x8*)(sAct + arow + ks * 32 + quad * 8);
#pragma unroll
  for (int i = 0; i < 4; ++i) acc[i] = (f32x4){0, 0, 0, 0};
#pragma unroll
  for (int ntl = 0; ntl < 4; ++ntl) {
    const int n = (nh * 4 + ntl) * 16 + col;
#pragma unroll
    for (int ks = 0; ks < 4; ++ks) {
      bf16x8 bb = *(const bf16x8*)(Wg2 + n * 128 + ks * 32 + quad * 8);
      acc[ntl] = __builtin_amdgcn_mfma_f32_16x16x32_bf16(A[ks], bb, acc[ntl], 0, 0, 0);
    }
  }
#pragma unroll
  for (int ntl = 0; ntl < 4; ++ntl) {
    const int n = (nh * 4 + ntl) * 16 + col;
    ushort4 pk;
    pk.x = (unsigned short)f2bf(acc[ntl][0]);
    pk.y = (unsigned short)f2bf(acc[ntl][1]);
    pk.z = (unsigned short)f2bf(acc[ntl][2]);
    pk.w = (unsigned short)f2bf(acc[ntl][3]);
    *(ushort4*)(sT + n * 72 + rg * 16 + quad * 4) = pk;
  }
  __syncthreads();

  // ---- AGG2 ----
#pragma unroll
  for (int i = 0; i < 4; ++i) acc[i] = (f32x4){0, 0, 0, 0};
#pragma unroll
  for (int ntl = 0; ntl < 4; ++ntl) {
    const int n = (nh * 4 + ntl) * 16 + col;
#pragma unroll
    for (int ks = 0; ks < 2; ++ks) {
      bf16x8 bb = *(const bf16x8*)(sT + n * 72 + ks * 32 + quad * 8);
      acc[ntl] = __builtin_amdgcn_mfma_f32_16x16x32_bf16(Ah[ks], bb, acc[ntl], 0, 0, 0);
    }
  }
#pragma unroll
  for (int ntl = 0; ntl < 4; ++ntl) {
    const int n = (nh * 4 + ntl) * 16 + col;
    const float bv = b_g2[n];
#pragma unroll
    for (int reg = 0; reg < 4; ++reg)
      sAct[crow0 + reg * 136 + n] = f2bf(fmaxf(acc[ntl][reg] + bv, 0.0f));
  }
  __syncthreads();

  // ---- HEAD ----
  if (tid < 320) {
    const int j = tid / 5, o = tid - 5 * j;
    float a0 = 0.0f;
#pragma unroll
    for (int k8 = 0; k8 < 16; ++k8) {
      union { bf16x8 v; unsigned short u[8]; } h;
      h.v = *(const bf16x8*)(sAct + j * 136 + k8 * 8);
#pragma unroll
      for (int jj = 0; jj < 8; ++jj)
        a0 = fmaf(bf2f(h.u[jj]), sWo[o * 128 + k8 * 8 + jj], a0);
    }
    out[(b * 64 + j) * 5 + o] = a0 + b_o[o];
  }
}

extern "C" void kernel_launch(void* const* d_in, const int* in_sizes, int n_in,
                              void* d_out, int out_size, void* d_ws, size_t ws_size,
                              hipStream_t stream) {
  const float* x    = (const float*)d_in[0];
  const float* gso  = (const float*)d_in[1];
  const float* w_c1 = (const float*)d_in[2];
  const float* b_c1 = (const float*)d_in[3];
  const float* g_b1 = (const float*)d_in[4];
  const float* e_b1 = (const float*)d_in[5];
  const float* w_c2 = (const float*)d_in[6];
  const float* b_c2 = (const float*)d_in[7];
  const float* g_b2 = (const float*)d_in[8];
  const float* e_b2 = (const float*)d_in[9];
  const float* w_c3 = (const float*)d_in[10];
  const float* b_c3 = (const float*)d_in[11];
  const float* g_b3 = (const float*)d_in[12];
  const float* e_b3 = (const float*)d_in[13];
  const float* w_fc = (const float*)d_in[14];
  const float* b_fc = (const float*)d_in[15];
  const float* w_g1 = (const float*)d_in[16];
  const float* b_g1 = (const float*)d_in[17];
  const float* w_g2 = (const float*)d_in[18];
  const float* b_g2 = (const float*)d_in[19];
  const float* w_o  = (const float*)d_in[20];
  const float* b_o  = (const float*)d_in[21];
  float* out = (float*)d_out;
  char* ws = (char*)d_ws;

  // workspace layout (bytes) — NO ALIASING, total ~4.5 MB
  short* c3  = (short*)(ws + 0);         //  4,194,304
  short* B1  = (short*)(ws + 4194304);   //  4,096
  short* B2  = (short*)(ws + 4198400);   //  36,864
  short* B3  = (short*)(ws + 4235264);   //  147,456
  short* Wfc = (short*)(ws + 4382720);   //  32,768
  short* Wg1 = (short*)(ws + 4415488);   //  32,768
  short* Wg2 = (short*)(ws + 4448256);   //  32,768

  pack_all<<<560, 256, 0, stream>>>(w_c1, w_c2, w_c3, w_fc, w_g1, w_g2,
                                    B1, B2, B3, Wfc, Wg1, Wg2);
  conv_all<<<1024, 256, 0, stream>>>(x, B1, B2, B3, b_c1, g_b1, e_b1,
                                     b_c2, g_b2, e_b2, b_c3, g_b3, e_b3, c3);
  fused_dense<<<256, 512, 0, stream>>>(c3, gso, Wfc, Wg1, Wg2, b_fc, b_g1,
                                       b_g2, w_o, b_o, out);
}

// Round 10
// 155.888 us; speedup vs baseline: 1.1618x; 1.1360x over previous
//
#include <hip/hip_runtime.h>
#include <math.h>

// Net_19335942767008 round 10: fix r9's self-inflicted LDS bank conflicts.
// sc1/sc2 unpadded (32/64-short cells = contiguous wave reads); B3 repacked to
// fragment-order in GLOBAL and read directly (L1 broadcast, no LDS, no P3
// barriers); B1/B2 fragment-order too. Math value-identical to rounds 7-9.

typedef __attribute__((ext_vector_type(8))) short bf16x8;
typedef __attribute__((ext_vector_type(4))) float f32x4;

__device__ __forceinline__ short f2bf(float f) {
  union { float f; unsigned u; } v; v.f = f;
  unsigned r = v.u + 0x7fffu + ((v.u >> 16) & 1u);
  return (short)(r >> 16);
}
__device__ __forceinline__ float bf2f(unsigned short u) {
  union { unsigned u; float f; } v; v.u = ((unsigned)u) << 16;
  return v.f;
}

// ---------- all weight packs (fragment order for convs) ----------
__global__ __launch_bounds__(256) void pack_all(
    const float* __restrict__ w_c1, const float* __restrict__ w_c2,
    const float* __restrict__ w_c3, const float* __restrict__ w_fc,
    const float* __restrict__ w_g1, const float* __restrict__ w_g2,
    short* __restrict__ B1, short* __restrict__ B2, short* __restrict__ B3,
    short* __restrict__ Wfc, short* __restrict__ Wg1, short* __restrict__ Wg2) {
  int idx = blockIdx.x * 256 + threadIdx.x;
  if (idx < 2048) {  // B1f: frag f = nt*2+ks', elem = lane*8+j
    int j = idx & 7, lane = (idx >> 3) & 63, f = idx >> 9;
    int nt = f >> 1, ksp = f & 1;
    int col = lane & 15, quad = lane >> 4;
    int k = ksp * 32 + quad * 8 + j;
    int t = k >> 2, ic = k & 3;
    int oc = nt * 16 + col;
    float v = (t < 9 && ic < 3) ? w_c1[(oc * 3 + ic) * 9 + t] : 0.0f;
    B1[idx] = f2bf(v);
  } else if (idx < 20480) {  // B2f: frag f = nt*9+t
    int i2 = idx - 2048;
    int j = i2 & 7, lane = (i2 >> 3) & 63, f = i2 >> 9;
    int nt = f / 9, t = f - nt * 9;
    int col = lane & 15, quad = lane >> 4;
    int oc = nt * 16 + col, ic = quad * 8 + j;
    B2[i2] = f2bf(w_c2[(oc * 32 + ic) * 9 + t]);
  } else if (idx < 94208) {  // B3f: frag f = ng*18+ks
    int i3 = idx - 20480;
    int j = i3 & 7, lane = (i3 >> 3) & 63, f = i3 >> 9;
    int ng = f / 18, ks = f - ng * 18;
    int col = lane & 15, quad = lane >> 4;
    int oc = ng * 16 + col;
    int k = ks * 32 + quad * 8 + j;
    int t = k >> 6, ic = k & 63;
    B3[i3] = f2bf(w_c3[(oc * 64 + ic) * 9 + t]);
  } else if (idx < 110592) {
    int i = idx - 94208; Wfc[i] = f2bf(w_fc[i]);
  } else if (idx < 126976) {
    int i = idx - 110592; Wg1[i] = f2bf(w_g1[i]);
  } else if (idx < 143360) {
    int i = idx - 126976; Wg2[i] = f2bf(w_g2[i]);
  }
}

// ---------- fused conv stack: x [S,3,8,8] -> c3 [S,128] bf16 ----------
__global__ __launch_bounds__(256, 2) void conv_all(
    const float* __restrict__ x, const short* __restrict__ B1f,
    const short* __restrict__ B2f, const short* __restrict__ B3f,
    const float* __restrict__ b1, const float* __restrict__ g1,
    const float* __restrict__ e1, const float* __restrict__ b2,
    const float* __restrict__ g2, const float* __restrict__ e2,
    const float* __restrict__ b3, const float* __restrict__ g3,
    const float* __restrict__ e3, short* __restrict__ c3) {
  __shared__ short sFrame[16 * 400];  // padded input frames, 12.8 KB
  __shared__ short sc1[16 * 512];     // conv1 out, unpadded, 16 KB
  __shared__ short sc2[16 * 256];     // conv2 out, unpadded, 8 KB
  const int tid = threadIdx.x;
  const int s0 = blockIdx.x * 16;
  const int lane = tid & 63, w = tid >> 6;
  const int col = lane & 15, quad = lane >> 4;
  const int m = lane & 15;

  // ---- P0: zero + fill 16 padded [10][10][4] bf16 frames ----
  for (int i = tid; i < 800; i += 256)
    *(uint4*)(sFrame + i * 8) = (uint4){0, 0, 0, 0};
  __syncthreads();
#pragma unroll
  for (int it = 0; it < 4; ++it) {
    int p = it * 256 + tid;
    int si = p >> 6, pix = p & 63;
    int y = pix >> 3, xx2 = pix & 7;
    const float* xb = x + (s0 + si) * 192 + pix;
    ushort4 o;
    o.x = (unsigned short)f2bf(xb[0]);
    o.y = (unsigned short)f2bf(xb[64]);
    o.z = (unsigned short)f2bf(xb[128]);
    o.w = 0;
    *(ushort4*)(sFrame + si * 400 + ((y + 1) * 10 + xx2 + 1) * 4) = o;
  }
  __syncthreads();

  // ---- P1: conv1 (wave w -> samples w*4..w*4+3) -> sc1 ----
  {
    bf16x8 Bf[2][2];
#pragma unroll
    for (int nt = 0; nt < 2; ++nt)
#pragma unroll
      for (int ks = 0; ks < 2; ++ks)
        Bf[nt][ks] = *(const bf16x8*)(B1f + ((nt * 2 + ks) << 9) + lane * 8);
    float Abn[2], Cbn[2];
#pragma unroll
    for (int nt = 0; nt < 2; ++nt) {
      int oc = nt * 16 + col;
      float a = g1[oc] * rsqrtf(1.0f + 1e-5f);
      Abn[nt] = a;
      Cbn[nt] = fmaf(b1[oc], a, e1[oc]);
    }
    const int t0 = 2 * quad, t1 = t0 + 1;
    const int ky0 = t0 / 3, kx0 = t0 - 3 * (t0 / 3);
    const int ky1 = t1 / 3, kx1 = t1 - 3 * (t1 / 3);
    const int pl = m >> 2, sub = m & 3;
    const int dy = sub >> 1, dx = sub & 1;
    const uint2 z2 = {0u, 0u};
#pragma unroll
    for (int sl = 0; sl < 4; ++sl) {
      const int si = w * 4 + sl;
      const short* xb = sFrame + si * 400;
#pragma unroll
      for (int tile = 0; tile < 4; ++tile) {
        const int pi = tile * 4 + pl;
        const int py = pi >> 2, px = pi & 3;
        const int cy = 2 * py + dy, cx = 2 * px + dx;
        union { bf16x8 v; uint2 u[2]; } a0, a1;
        a0.u[0] = *(const uint2*)(xb + ((cy + ky0) * 10 + cx + kx0) * 4);
        a0.u[1] = *(const uint2*)(xb + ((cy + ky1) * 10 + cx + kx1) * 4);
        uint2 u8 = *(const uint2*)(xb + ((cy + 2) * 10 + cx + 2) * 4);
        a1.u[0] = (quad == 0) ? u8 : z2;
        a1.u[1] = z2;
        f32x4 acc0 = {0, 0, 0, 0}, acc1 = {0, 0, 0, 0};
        acc0 = __builtin_amdgcn_mfma_f32_16x16x32_bf16(a0.v, Bf[0][0], acc0, 0, 0, 0);
        acc0 = __builtin_amdgcn_mfma_f32_16x16x32_bf16(a1.v, Bf[0][1], acc0, 0, 0, 0);
        acc1 = __builtin_amdgcn_mfma_f32_16x16x32_bf16(a0.v, Bf[1][0], acc1, 0, 0, 0);
        acc1 = __builtin_amdgcn_mfma_f32_16x16x32_bf16(a1.v, Bf[1][1], acc1, 0, 0, 0);
        const int piq = tile * 4 + quad;
#pragma unroll
        for (int nt = 0; nt < 2; ++nt) {
          f32x4 acc = nt ? acc1 : acc0;
          float p0 = fmaf(acc[0], Abn[nt], Cbn[nt]);
          float p1 = fmaf(acc[1], Abn[nt], Cbn[nt]);
          float p2 = fmaf(acc[2], Abn[nt], Cbn[nt]);
          float p3 = fmaf(acc[3], Abn[nt], Cbn[nt]);
          float mx = fmaxf(fmaxf(fmaxf(p0, p1), fmaxf(p2, p3)), 0.0f);
          sc1[si * 512 + piq * 32 + nt * 16 + col] = f2bf(mx);
        }
      }
    }
  }
  __syncthreads();

  // ---- P2: conv2 (wave w -> samples w*4..w*4+3), A from sc1 -> sc2 ----
  {
    bf16x8 Bf[4][9];
#pragma unroll
    for (int nt = 0; nt < 4; ++nt)
#pragma unroll
      for (int t = 0; t < 9; ++t)
        Bf[nt][t] = *(const bf16x8*)(B2f + ((nt * 9 + t) << 9) + lane * 8);
    float Abn[4], Cbn[4];
#pragma unroll
    for (int nt = 0; nt < 4; ++nt) {
      int oc = nt * 16 + col;
      float a = g2[oc] * rsqrtf(1.0f + 1e-5f);
      Abn[nt] = a;
      Cbn[nt] = fmaf(b2[oc], a, e2[oc]);
    }
    const int q2 = m >> 2, sub = m & 3;
    const int cy = 2 * (q2 >> 1) + (sub >> 1);
    const int cx = 2 * (q2 & 1) + (sub & 1);
    int off[9];
    bool valid[9];
#pragma unroll
    for (int t = 0; t < 9; ++t) {
      int ky = t / 3, kx = t - 3 * (t / 3);
      int yy = cy + ky - 1, xx = cx + kx - 1;
      valid[t] = ((unsigned)yy < 4u) && ((unsigned)xx < 4u);
      int yc = min(max(yy, 0), 3), xc = min(max(xx, 0), 3);
      off[t] = (yc * 4 + xc) * 32 + quad * 8;
    }
    const bf16x8 zf = {0, 0, 0, 0, 0, 0, 0, 0};
#pragma unroll
    for (int sl = 0; sl < 4; ++sl) {
      const int si = w * 4 + sl;
      const short* ib = sc1 + si * 512;
      f32x4 acc[4];
#pragma unroll
      for (int nt = 0; nt < 4; ++nt) acc[nt] = (f32x4){0, 0, 0, 0};
#pragma unroll
      for (int t = 0; t < 9; ++t) {
        bf16x8 a = *(const bf16x8*)(ib + off[t]);
        if (!valid[t]) a = zf;
#pragma unroll
        for (int nt = 0; nt < 4; ++nt)
          acc[nt] = __builtin_amdgcn_mfma_f32_16x16x32_bf16(a, Bf[nt][t], acc[nt], 0, 0, 0);
      }
#pragma unroll
      for (int nt = 0; nt < 4; ++nt) {
        float p0 = fmaf(acc[nt][0], Abn[nt], Cbn[nt]);
        float p1 = fmaf(acc[nt][1], Abn[nt], Cbn[nt]);
        float p2 = fmaf(acc[nt][2], Abn[nt], Cbn[nt]);
        float p3 = fmaf(acc[nt][3], Abn[nt], Cbn[nt]);
        float mx = fmaxf(fmaxf(fmaxf(p0, p1), fmaxf(p2, p3)), 0.0f);
        sc2[si * 256 + quad * 64 + nt * 16 + col] = f2bf(mx);
      }
    }
  }
  __syncthreads();

  // ---- P3: conv3, A from sc2, B fragments direct from global (L1) ----
  {
    const int cp = m & 3, sl3 = m >> 2;
    const int cy = cp >> 1, cx = cp & 1;
    const short* ib = sc2 + (w * 4 + sl3) * 256;
    bf16x8 A[18];
    const bf16x8 zf = {0, 0, 0, 0, 0, 0, 0, 0};
#pragma unroll
    for (int ks = 0; ks < 18; ++ks) {
      int t = ks >> 1;
      int ky = t / 3, kx = t - 3 * (t / 3);
      int iy = cy + ky - 1, ix = cx + kx - 1;
      bool valid = ((unsigned)iy < 2u) && ((unsigned)ix < 2u);
      int iyc = min(max(iy, 0), 1), ixc = min(max(ix, 0), 1);
      bf16x8 a = *(const bf16x8*)(ib + (iyc * 2 + ixc) * 64 + (ks & 1) * 32 + quad * 8);
      A[ks] = valid ? a : zf;
    }
    f32x4 acc[8];
#pragma unroll
    for (int i = 0; i < 8; ++i) acc[i] = (f32x4){0, 0, 0, 0};
#pragma unroll
    for (int ng = 0; ng < 8; ++ng) {
#pragma unroll
      for (int ks = 0; ks < 18; ++ks) {
        bf16x8 b = *(const bf16x8*)(B3f + (((ng * 18 + ks) << 6) + lane) * 8);
        acc[ng] = __builtin_amdgcn_mfma_f32_16x16x32_bf16(A[ks], b, acc[ng], 0, 0, 0);
      }
    }
    const int sample = s0 + w * 4 + quad;
#pragma unroll
    for (int ng = 0; ng < 8; ++ng) {
      int oc = ng * 16 + col;
      float a = g3[oc] * rsqrtf(1.0f + 1e-5f);
      float cc = fmaf(b3[oc], a, e3[oc]);
      float p0 = fmaf(acc[ng][0], a, cc);
      float p1 = fmaf(acc[ng][1], a, cc);
      float p2 = fmaf(acc[ng][2], a, cc);
      float p3 = fmaf(acc[ng][3], a, cc);
      float mx = fmaxf(fmaxf(fmaxf(p0, p1), fmaxf(p2, p3)), 0.0f);
      c3[sample * 128 + oc] = f2bf(mx);
    }
  }
}

// ---------- fused dense tail: one block (512 thr, 8 waves) per batch ----------
__global__ __launch_bounds__(512) void fused_dense(
    const short* __restrict__ c3, const float* __restrict__ gso,
    const short* __restrict__ Wfc, const short* __restrict__ Wg1,
    const short* __restrict__ Wg2, const float* __restrict__ b_fc,
    const float* __restrict__ b_g1, const float* __restrict__ b_g2,
    const float* __restrict__ w_o, const float* __restrict__ b_o,
    float* __restrict__ out) {
  __shared__ short sAct[64 * 136];
  __shared__ short sT[128 * 72];
  __shared__ short sAhat[64 * 72];
  __shared__ float sDinv[64];
  __shared__ float sWo[640];
  const int tid = threadIdx.x;
  const int b = blockIdx.x;
  float* sG = (float*)sT;
  for (int i = tid; i < 4096; i += 512) sG[i] = gso[b * 4096 + i];
  for (int i = tid; i < 640; i += 512) sWo[i] = w_o[i];
  __syncthreads();
  if (tid < 64) {
    float ssum = 1.0f;
    for (int j = 0; j < 64; ++j) ssum += sG[j * 64 + tid];
    sDinv[tid] = rsqrtf(ssum);
  }
  __syncthreads();
  for (int i = tid; i < 4096; i += 512) {
    int r = i >> 6, c = i & 63;
    float v = sDinv[r] * (sG[i] + (r == c ? 1.0f : 0.0f)) * sDinv[c];
    sAhat[r * 72 + c] = f2bf(v);
  }
  for (int i = tid; i < 1024; i += 512) {
    int r = i >> 4, seg = i & 15;
    *(bf16x8*)(sAct + r * 136 + seg * 8) =
        *(const bf16x8*)(c3 + (b * 64 + r) * 128 + seg * 8);
  }
  __syncthreads();
  const int lane = tid & 63, w8 = tid >> 6;
  const int rg = w8 >> 1, nh = w8 & 1;
  const int col = lane & 15, quad = lane >> 4;
  const int arow = (rg * 16 + col) * 136;
  const int crow0 = (rg * 16 + quad * 4) * 136;
  bf16x8 A[4];
  f32x4 acc[4];

  // ---- FC ----
#pragma unroll
  for (int ks = 0; ks < 4; ++ks)
    A[ks] = *(const bf16x8*)(sAct + arow + ks * 32 + quad * 8);
  __syncthreads();
#pragma unroll
  for (int i = 0; i < 4; ++i) acc[i] = (f32x4){0, 0, 0, 0};
#pragma unroll
  for (int ntl = 0; ntl < 4; ++ntl) {
    const int n = (nh * 4 + ntl) * 16 + col;
#pragma unroll
    for (int ks = 0; ks < 4; ++ks) {
      bf16x8 bb = *(const bf16x8*)(Wfc + n * 128 + ks * 32 + quad * 8);
      acc[ntl] = __builtin_amdgcn_mfma_f32_16x16x32_bf16(A[ks], bb, acc[ntl], 0, 0, 0);
    }
  }
#pragma unroll
  for (int ntl = 0; ntl < 4; ++ntl) {
    const int n = (nh * 4 + ntl) * 16 + col;
    const float bv = b_fc[n];
#pragma unroll
    for (int reg = 0; reg < 4; ++reg)
      sAct[crow0 + reg * 136 + n] = f2bf(fmaxf(acc[ntl][reg] + bv, 0.0f));
  }
  __syncthreads();

  // ---- G1 -> sT (transposed) ----
#pragma unroll
  for (int ks = 0; ks < 4; ++ks)
    A[ks] = *(const bf16x8*)(sAct + arow + ks * 32 + quad * 8);
#pragma unroll
  for (int i = 0; i < 4; ++i) acc[i] = (f32x4){0, 0, 0, 0};
#pragma unroll
  for (int ntl = 0; ntl < 4; ++ntl) {
    const int n = (nh * 4 + ntl) * 16 + col;
#pragma unroll
    for (int ks = 0; ks < 4; ++ks) {
      bf16x8 bb = *(const bf16x8*)(Wg1 + n * 128 + ks * 32 + quad * 8);
      acc[ntl] = __builtin_amdgcn_mfma_f32_16x16x32_bf16(A[ks], bb, acc[ntl], 0, 0, 0);
    }
  }
#pragma unroll
  for (int ntl = 0; ntl < 4; ++ntl) {
    const int n = (nh * 4 + ntl) * 16 + col;
    ushort4 pk;
    pk.x = (unsigned short)f2bf(acc[ntl][0]);
    pk.y = (unsigned short)f2bf(acc[ntl][1]);
    pk.z = (unsigned short)f2bf(acc[ntl][2]);
    pk.w = (unsigned short)f2bf(acc[ntl][3]);
    *(ushort4*)(sT + n * 72 + rg * 16 + quad * 4) = pk;
  }
  __syncthreads();

  // ---- AGG1 ----
  bf16x8 Ah[2];
#pragma unroll
  for (int ks = 0; ks < 2; ++ks)
    Ah[ks] = *(const bf16x8*)(sAhat + (rg * 16 + col) * 72 + ks * 32 + quad * 8);
#pragma unroll
  for (int i = 0; i < 4; ++i) acc[i] = (f32x4){0, 0, 0, 0};
#pragma unroll
  for (int ntl = 0; ntl < 4; ++ntl) {
    const int n = (nh * 4 + ntl) * 16 + col;
#pragma unroll
    for (int ks = 0; ks < 2; ++ks) {
      bf16x8 bb = *(const bf16x8*)(sT + n * 72 + ks * 32 + quad * 8);
      acc[ntl] = __builtin_amdgcn_mfma_f32_16x16x32_bf16(Ah[ks], bb, acc[ntl], 0, 0, 0);
    }
  }
#pragma unroll
  for (int ntl = 0; ntl < 4; ++ntl) {
    const int n = (nh * 4 + ntl) * 16 + col;
    const float bv = b_g1[n];
#pragma unroll
    for (int reg = 0; reg < 4; ++reg)
      sAct[crow0 + reg * 136 + n] = f2bf(fmaxf(acc[ntl][reg] + bv, 0.0f));
  }
  __syncthreads();

  // ---- G2 -> sT ----
#pragma unroll
  for (int ks = 0; ks < 4; ++ks)
    A[ks] = *(const bf16x8*)(sAct + arow + ks * 32 + quad * 8);
#pragma unroll
  for (int i = 0; i < 4; ++i) acc[i] = (f32x4){0, 0, 0, 0};
#pragma unroll
  for (int ntl = 0; ntl < 4; ++ntl) {
    const int n = (nh * 4 + ntl) * 16 + col;
#pragma unroll
    for (int ks = 0; ks < 4; ++ks) {
      bf16x8 bb = *(const bf16x8*)(Wg2 + n * 128 + ks * 32 + quad * 8);
      acc[ntl] = __builtin_amdgcn_mfma_f32_16x16x32_bf16(A[ks], bb, acc[ntl], 0, 0, 0);
    }
  }
#pragma unroll
  for (int ntl = 0; ntl < 4; ++ntl) {
    const int n = (nh * 4 + ntl) * 16 + col;
    ushort4 pk;
    pk.x = (unsigned short)f2bf(acc[ntl][0]);
    pk.y = (unsigned short)f2bf(acc[ntl][1]);
    pk.z = (unsigned short)f2bf(acc[ntl][2]);
    pk.w = (unsigned short)f2bf(acc[ntl][3]);
    *(ushort4*)(sT + n * 72 + rg * 16 + quad * 4) = pk;
  }
  __syncthreads();

  // ---- AGG2 ----
#pragma unroll
  for (int i = 0; i < 4; ++i) acc[i] = (f32x4){0, 0, 0, 0};
#pragma unroll
  for (int ntl = 0; ntl < 4; ++ntl) {
    const int n = (nh * 4 + ntl) * 16 + col;
#pragma unroll
    for (int ks = 0; ks < 2; ++ks) {
      bf16x8 bb = *(const bf16x8*)(sT + n * 72 + ks * 32 + quad * 8);
      acc[ntl] = __builtin_amdgcn_mfma_f32_16x16x32_bf16(Ah[ks], bb, acc[ntl], 0, 0, 0);
    }
  }
#pragma unroll
  for (int ntl = 0; ntl < 4; ++ntl) {
    const int n = (nh * 4 + ntl) * 16 + col;
    const float bv = b_g2[n];
#pragma unroll
    for (int reg = 0; reg < 4; ++reg)
      sAct[crow0 + reg * 136 + n] = f2bf(fmaxf(acc[ntl][reg] + bv, 0.0f));
  }
  __syncthreads();

  // ---- HEAD ----
  if (tid < 320) {
    const int j = tid / 5, o = tid - 5 * j;
    float a0 = 0.0f;
#pragma unroll
    for (int k8 = 0; k8 < 16; ++k8) {
      union { bf16x8 v; unsigned short u[8]; } h;
      h.v = *(const bf16x8*)(sAct + j * 136 + k8 * 8);
#pragma unroll
      for (int jj = 0; jj < 8; ++jj)
        a0 = fmaf(bf2f(h.u[jj]), sWo[o * 128 + k8 * 8 + jj], a0);
    }
    out[(b * 64 + j) * 5 + o] = a0 + b_o[o];
  }
}

extern "C" void kernel_launch(void* const* d_in, const int* in_sizes, int n_in,
                              void* d_out, int out_size, void* d_ws, size_t ws_size,
                              hipStream_t stream) {
  const float* x    = (const float*)d_in[0];
  const float* gso  = (const float*)d_in[1];
  const float* w_c1 = (const float*)d_in[2];
  const float* b_c1 = (const float*)d_in[3];
  const float* g_b1 = (const float*)d_in[4];
  const float* e_b1 = (const float*)d_in[5];
  const float* w_c2 = (const float*)d_in[6];
  const float* b_c2 = (const float*)d_in[7];
  const float* g_b2 = (const float*)d_in[8];
  const float* e_b2 = (const float*)d_in[9];
  const float* w_c3 = (const float*)d_in[10];
  const float* b_c3 = (const float*)d_in[11];
  const float* g_b3 = (const float*)d_in[12];
  const float* e_b3 = (const float*)d_in[13];
  const float* w_fc = (const float*)d_in[14];
  const float* b_fc = (const float*)d_in[15];
  const float* w_g1 = (const float*)d_in[16];
  const float* b_g1 = (const float*)d_in[17];
  const float* w_g2 = (const float*)d_in[18];
  const float* b_g2 = (const float*)d_in[19];
  const float* w_o  = (const float*)d_in[20];
  const float* b_o  = (const float*)d_in[21];
  float* out = (float*)d_out;
  char* ws = (char*)d_ws;

  // workspace layout (bytes) — NO ALIASING, total ~4.5 MB
  short* c3  = (short*)(ws + 0);         //  4,194,304
  short* B1  = (short*)(ws + 4194304);   //  4,096   (fragment order)
  short* B2  = (short*)(ws + 4198400);   //  36,864  (fragment order)
  short* B3  = (short*)(ws + 4235264);   //  147,456 (fragment order)
  short* Wfc = (short*)(ws + 4382720);   //  32,768
  short* Wg1 = (short*)(ws + 4415488);   //  32,768
  short* Wg2 = (short*)(ws + 4448256);   //  32,768

  pack_all<<<560, 256, 0, stream>>>(w_c1, w_c2, w_c3, w_fc, w_g1, w_g2,
                                    B1, B2, B3, Wfc, Wg1, Wg2);
  conv_all<<<1024, 256, 0, stream>>>(x, B1, B2, B3, b_c1, g_b1, e_b1,
                                     b_c2, g_b2, e_b2, b_c3, g_b3, e_b3, c3);
  fused_dense<<<256, 512, 0, stream>>>(c3, gso, Wfc, Wg1, Wg2, b_fc, b_g1,
                                       b_g2, w_o, b_o, out);
}